// Round 8
// baseline (333.504 us; speedup 1.0000x reference)
//
#include <hip/hip_runtime.h>

#define H 224
#define W 224
#define B 32
#define C 96

typedef float nfloat4 __attribute__((ext_vector_type(4)));

// ws: nbuf[b][slice8][pi][pj] = 32*8*256 floats = 256 KiB.
// Every entry stored exactly once per replay (no zeroing, no global atomics).

// Pipelined fused kernel, GROUP=2 batches/stage, 17 launches.
//   blocks [0, nCount*128)   : norms, unit=(b, pi, slice∈8)  (fresh HBM read -> MALL)
//   blocks [nCount*128, end) : roll, 672 blocks/batch (MALL-hot re-read, nt writes)
// GROUP=2 keeps the inter-launch MALL footprint (~115 MB) below 256 MB so the
// previous group's input survives until its re-read.

template<int R>
__device__ __forceinline__ void roll_body(const float* __restrict__ xb,
                                          float* __restrict__ ob,
                                          int c0, int h0, int sh0,
                                          int q, int lane) {
    int v = lane + q;  if (v >= 56) v -= 56;
    int nl = lane + 1; if (nl >= 56) nl = 0;
    int sh = sh0;
    #pragma unroll
    for (int it = 0; it < 8; ++it) {
        int h = h0 + it * 4;                       // stays < 224 within a block
        const float4* srow = (const float4*)(xb + ((size_t)c0 * H + sh) * W);
        nfloat4*      drow = (nfloat4*)     (ob + ((size_t)c0 * H + h)  * W);
        float4 a = srow[v];                        // regular load: probe MALL (hot from prev stage)
        float4 o;
        if (R == 0) {
            o = a;
        } else {
            float nx = __shfl(a.x, nl);
            float ny = (R >= 2) ? __shfl(a.y, nl) : 0.0f;
            float nz = (R == 3) ? __shfl(a.z, nl) : 0.0f;
            if (R == 1) { o.x = a.y; o.y = a.z; o.z = a.w; o.w = nx; }
            if (R == 2) { o.x = a.z; o.y = a.w; o.z = nx;  o.w = ny; }
            if (R == 3) { o.x = a.w; o.y = nx;  o.z = ny;  o.w = nz; }
        }
        nfloat4 on = { o.x, o.y, o.z, o.w };
        __builtin_nontemporal_store(on, drow + lane);   // out is dead data: don't pollute MALL
        sh += 4; if (sh >= H) sh -= H;
    }
}

__global__ void fused_kernel(const float* __restrict__ x, float* __restrict__ out,
                             float* __restrict__ nbuf,
                             int nStart, int nCount, int rStart, int rCount) {
    int wave = threadIdx.x >> 6;
    int lane = threadIdx.x & 63;

    if ((int)blockIdx.x < nCount * 128) {
        // -------- norms for one (b, pi, slice∈8); wave = 3 channel streams --------
        int b     = nStart + ((int)blockIdx.x >> 7);
        int sub   = blockIdx.x & 127;
        int pi    = sub >> 3;
        int slice = sub & 7;

        __shared__ float bins[16];
        if (threadIdx.x < 16) bins[threadIdx.x] = 0.0f;
        __syncthreads();

        if (lane < 56) {
            const float* base = x + (size_t)b * C * H * W;
            int c = slice * 12 + wave * 3;          // channels c, c+1, c+2
            const size_t HW4 = (size_t)H * W / 4;   // float4 units per channel
            const float4* p = (const float4*)(base + ((size_t)c * H + pi) * W);
            float a0=0.f,a1=0.f,a2=0.f,a3=0.f;
            float b0=0.f,b1=0.f,b2=0.f,b3=0.f;
            float c0_=0.f,c1=0.f,c2=0.f,c3=0.f;
            const size_t giStep = (size_t)16 * W / 4;   // 16 rows, float4 units
            #pragma unroll 2
            for (int gi = 0; gi < 14; ++gi) {
                float4 va = p[lane];
                float4 vb = (p + HW4)[lane];
                float4 vc = (p + 2 * HW4)[lane];
                a0 += va.x * va.x; a1 += va.y * va.y; a2 += va.z * va.z; a3 += va.w * va.w;
                b0 += vb.x * vb.x; b1 += vb.y * vb.y; b2 += vb.z * vb.z; b3 += vb.w * vb.w;
                c0_ += vc.x * vc.x; c1 += vc.y * vc.y; c2 += vc.z * vc.z; c3 += vc.w * vc.w;
                p += giStep;
            }
            a0 += b0 + c0_;
            a1 += b1 + c1;
            a2 += b2 + c2;
            a3 += b3 + c3;
            int bse = (lane & 3) << 2;              // pj of v.x = (4*lane)%16
            atomicAdd(&bins[bse + 0], a0);
            atomicAdd(&bins[bse + 1], a1);
            atomicAdd(&bins[bse + 2], a2);
            atomicAdd(&bins[bse + 3], a3);
        }
        __syncthreads();
        if (threadIdx.x < 16)
            nbuf[((b * 8 + slice) * 16 + pi) * 16 + threadIdx.x] = bins[threadIdx.x];
    } else {
        // ---------------- roll for 32 rows of one batch -----------------
        int rIdx  = blockIdx.x - nCount * 128;
        int b     = rStart + rIdx / 672;
        int local = rIdx % 672;

        // per-block argmax over 256 bins (sum of 8 slice partials; deterministic)
        const float* nb = nbuf + (size_t)b * 2048;
        int t = threadIdx.x;
        float v = 0.0f;
        #pragma unroll
        for (int s = 0; s < 8; ++s) v += nb[s * 256 + t];
        int idx = t;
        for (int off = 32; off > 0; off >>= 1) {
            float ov = __shfl_down(v, off);
            int   oi = __shfl_down(idx, off);
            if (ov > v || (ov == v && oi < idx)) { v = ov; idx = oi; }
        }
        __shared__ float wv[4];
        __shared__ int   wi[4];
        __shared__ int   ssi, ssj;
        if (lane == 0) { wv[wave] = v; wi[wave] = idx; }
        __syncthreads();
        if (threadIdx.x == 0) {
            float bv = wv[0]; int bi = wi[0];
            #pragma unroll
            for (int w = 1; w < 4; ++w)
                if (wv[w] > bv) { bv = wv[w]; bi = wi[w]; }   // strict >: earliest wave wins ties
            ssi = bi >> 4; ssj = bi & 15;
        }
        __syncthreads();
        int si = ssi, sj = ssj;

        if (lane < 56) {
            int q = sj >> 2, r = sj & 3;
            int c0 = local / 7;
            int h0 = (local % 7) * 32 + wave;
            int sh0 = h0 + si; if (sh0 >= H) sh0 -= H;
            const float* xb = x   + (size_t)b * C * H * W;
            float*       ob = out + (size_t)b * C * H * W;
            switch (r) {
                case 0: roll_body<0>(xb, ob, c0, h0, sh0, q, lane); break;
                case 1: roll_body<1>(xb, ob, c0, h0, sh0, q, lane); break;
                case 2: roll_body<2>(xb, ob, c0, h0, sh0, q, lane); break;
                default: roll_body<3>(xb, ob, c0, h0, sh0, q, lane); break;
            }
        }
    }
}

extern "C" void kernel_launch(void* const* d_in, const int* in_sizes, int n_in,
                              void* d_out, int out_size, void* d_ws, size_t ws_size,
                              hipStream_t stream) {
    const float* x = (const float*)d_in[0];
    float* outp = (float*)d_out;
    float* nbuf = (float*)d_ws;

    const int GROUP = 2;                 // batches per pipeline stage
    const int NSTAGE = B / GROUP;        // 16
    for (int i = 0; i <= NSTAGE; ++i) {
        int nStart = GROUP * i;
        int nCount = (i < NSTAGE) ? GROUP : 0;
        int rStart = GROUP * (i - 1);
        int rCount = (i > 0) ? GROUP : 0;
        int blocks = nCount * 128 + rCount * 672;
        fused_kernel<<<blocks, 256, 0, stream>>>(x, outp, nbuf,
                                                 nStart, nCount, rStart, rCount);
    }
}

// Round 9
// 293.426 us; speedup vs baseline: 1.1366x; 1.1366x over previous
//
#include <hip/hip_runtime.h>

#define H 224
#define W 224
#define B 32
#define C 96

typedef float nfloat4 __attribute__((ext_vector_type(4)));

// ws: nbuf[b][slice8][pi][pj] = 32*8*256 floats = 256 KiB.
// Every entry stored exactly once per replay (no zeroing, no global atomics).
//
// Structure (post-R8): inter-launch L3 reuse is refuted on this part, so the
// 1.85 GB HBM traffic (read x twice + write out) is structural. Minimize
// launch-drain boundaries instead: 2 launches, all big streams non-temporal.

// -------- norms: grid dim3(128, 32); unit = (b, pi, slice in 8) --------
__global__ __launch_bounds__(256) void norms_kernel(const float* __restrict__ x,
                                                    float* __restrict__ nbuf) {
    int sub   = blockIdx.x;
    int b     = blockIdx.y;
    int pi    = sub >> 3;
    int slice = sub & 7;
    int wave  = threadIdx.x >> 6;
    int lane  = threadIdx.x & 63;

    __shared__ float bins[16];
    if (threadIdx.x < 16) bins[threadIdx.x] = 0.0f;
    __syncthreads();

    if (lane < 56) {
        const float* base = x + (size_t)b * C * H * W;
        int c = slice * 12 + wave * 3;          // channels c, c+1, c+2
        const size_t HW4 = (size_t)H * W / 4;   // float4 units per channel
        const nfloat4* p = (const nfloat4*)(base + ((size_t)c * H + pi) * W);
        float a0=0.f,a1=0.f,a2=0.f,a3=0.f;
        float b0=0.f,b1=0.f,b2=0.f,b3=0.f;
        float c0_=0.f,c1=0.f,c2=0.f,c3=0.f;
        const size_t giStep = (size_t)16 * W / 4;   // 16 rows, float4 units
        for (int gi = 0; gi < 14; ++gi) {
            nfloat4 va = __builtin_nontemporal_load(p + lane);
            nfloat4 vb = __builtin_nontemporal_load(p + HW4 + lane);
            nfloat4 vc = __builtin_nontemporal_load(p + 2 * HW4 + lane);
            a0 += va.x * va.x; a1 += va.y * va.y; a2 += va.z * va.z; a3 += va.w * va.w;
            b0 += vb.x * vb.x; b1 += vb.y * vb.y; b2 += vb.z * vb.z; b3 += vb.w * vb.w;
            c0_ += vc.x * vc.x; c1 += vc.y * vc.y; c2 += vc.z * vc.z; c3 += vc.w * vc.w;
            p += giStep;
        }
        a0 += b0 + c0_;
        a1 += b1 + c1;
        a2 += b2 + c2;
        a3 += b3 + c3;
        int bse = (lane & 3) << 2;              // pj of v.x = (4*lane)%16
        atomicAdd(&bins[bse + 0], a0);
        atomicAdd(&bins[bse + 1], a1);
        atomicAdd(&bins[bse + 2], a2);
        atomicAdd(&bins[bse + 3], a3);
    }
    __syncthreads();
    if (threadIdx.x < 16)
        nbuf[((b * 8 + slice) * 16 + pi) * 16 + threadIdx.x] = bins[threadIdx.x];
}

// -------- roll: grid dim3(672, 32); embedded per-block argmax --------
template<int R>
__device__ __forceinline__ void roll_body(const float* __restrict__ xb,
                                          float* __restrict__ ob,
                                          int c0, int h0, int sh0,
                                          int q, int lane) {
    int v = lane + q;  if (v >= 56) v -= 56;
    int nl = lane + 1; if (nl >= 56) nl = 0;
    int sh = sh0;
    #pragma unroll
    for (int it = 0; it < 8; ++it) {
        int h = h0 + it * 4;                       // stays < 224 within a block
        const nfloat4* srow = (const nfloat4*)(xb + ((size_t)c0 * H + sh) * W);
        nfloat4*       drow = (nfloat4*)      (ob + ((size_t)c0 * H + h)  * W);
        nfloat4 a = __builtin_nontemporal_load(srow + v);   // streaming: don't allocate
        nfloat4 o;
        if (R == 0) {
            o = a;
        } else {
            float nx = __shfl(a.x, nl);
            float ny = (R >= 2) ? __shfl(a.y, nl) : 0.0f;
            float nz = (R == 3) ? __shfl(a.z, nl) : 0.0f;
            if (R == 1) { o.x = a.y; o.y = a.z; o.z = a.w; o.w = nx; }
            if (R == 2) { o.x = a.z; o.y = a.w; o.z = nx;  o.w = ny; }
            if (R == 3) { o.x = a.w; o.y = nx;  o.z = ny;  o.w = nz; }
        }
        __builtin_nontemporal_store(o, drow + lane);        // dead data: don't pollute
        sh += 4; if (sh >= H) sh -= H;
    }
}

__global__ __launch_bounds__(256) void roll_kernel(const float* __restrict__ x,
                                                   float* __restrict__ out,
                                                   const float* __restrict__ nbuf) {
    int local = blockIdx.x;
    int b     = blockIdx.y;
    int wave  = threadIdx.x >> 6;
    int lane  = threadIdx.x & 63;

    // per-block argmax over 256 bins (sum of 8 slice partials; L2-hot, deterministic)
    const float* nb = nbuf + (size_t)b * 2048;
    int t = threadIdx.x;
    float v = 0.0f;
    #pragma unroll
    for (int s = 0; s < 8; ++s) v += nb[s * 256 + t];
    int idx = t;
    for (int off = 32; off > 0; off >>= 1) {
        float ov = __shfl_down(v, off);
        int   oi = __shfl_down(idx, off);
        if (ov > v || (ov == v && oi < idx)) { v = ov; idx = oi; }
    }
    __shared__ float wv[4];
    __shared__ int   wi[4];
    __shared__ int   ssi, ssj;
    if (lane == 0) { wv[wave] = v; wi[wave] = idx; }
    __syncthreads();
    if (threadIdx.x == 0) {
        float bv = wv[0]; int bi = wi[0];
        #pragma unroll
        for (int w = 1; w < 4; ++w)
            if (wv[w] > bv) { bv = wv[w]; bi = wi[w]; }   // strict >: earliest wave wins ties
        ssi = bi >> 4; ssj = bi & 15;
    }
    __syncthreads();
    int si = ssi, sj = ssj;

    if (lane < 56) {
        int q = sj >> 2, r = sj & 3;
        int c0 = local / 7;
        int h0 = (local % 7) * 32 + wave;
        int sh0 = h0 + si; if (sh0 >= H) sh0 -= H;
        const float* xb = x   + (size_t)b * C * H * W;
        float*       ob = out + (size_t)b * C * H * W;
        switch (r) {
            case 0: roll_body<0>(xb, ob, c0, h0, sh0, q, lane); break;
            case 1: roll_body<1>(xb, ob, c0, h0, sh0, q, lane); break;
            case 2: roll_body<2>(xb, ob, c0, h0, sh0, q, lane); break;
            default: roll_body<3>(xb, ob, c0, h0, sh0, q, lane); break;
        }
    }
}

extern "C" void kernel_launch(void* const* d_in, const int* in_sizes, int n_in,
                              void* d_out, int out_size, void* d_ws, size_t ws_size,
                              hipStream_t stream) {
    const float* x = (const float*)d_in[0];
    float* outp = (float*)d_out;
    float* nbuf = (float*)d_ws;

    norms_kernel<<<dim3(128, 32), 256, 0, stream>>>(x, nbuf);
    roll_kernel<<<dim3(672, 32), 256, 0, stream>>>(x, outp, nbuf);
}